// Round 1
// baseline (141.562 us; speedup 1.0000x reference)
//
#include <hip/hip_runtime.h>
#include <hip/hip_bf16.h>

#define S1 2048
#define S2 2048
#define FEAT 768
#define NB 8
#define BM 128
#define BN 128
#define BK 64

typedef __attribute__((ext_vector_type(8))) short bf16x8;
typedef __attribute__((ext_vector_type(4))) float f32x4;
typedef __attribute__((ext_vector_type(4))) unsigned short us4;

static __device__ __forceinline__ unsigned short f2bf(float x) {
    unsigned u = __builtin_bit_cast(unsigned, x);
    unsigned r = u + 0x7FFFu + ((u >> 16) & 1u);   // RNE
    return (unsigned short)(r >> 16);
}

// ---------------- Q/D pre-pass: one wave per row, fp32 exact ----------------
__global__ __launch_bounds__(256) void qd_kernel(
    const float* __restrict__ m1, const float* __restrict__ m2,
    const float* __restrict__ wq, const float* __restrict__ wd,
    float* __restrict__ Q, float* __restrict__ D) {
    int wave = threadIdx.x >> 6;
    int lane = threadIdx.x & 63;
    int g = blockIdx.x * 4 + wave;           // 0 .. 2*NB*S1-1
    const float* src; const float* w; float* dst; int row;
    if (g < NB * S1) { src = m1; w = wq; dst = Q; row = g; }
    else             { src = m2; w = wd; dst = D; row = g - NB * S1; }
    const float4* rp = (const float4*)(src + (size_t)row * FEAT);
    const float4* wp = (const float4*)w;
    float acc = 0.f;
#pragma unroll
    for (int i = 0; i < 3; ++i) {            // 768/4/64 = 3 float4 per lane
        float4 a = rp[lane + 64 * i];
        float4 b = wp[lane + 64 * i];
        acc += a.x * b.x + a.y * b.y + a.z * b.z + a.w * b.w;
    }
#pragma unroll
    for (int s = 32; s; s >>= 1) acc += __shfl_xor(acc, s, 64);
    if (lane == 0) dst[row] = acc;
}

// ---------------- batched NT GEMM: out = (m1*wc) @ m2^T + Q + D ----------------
__global__ __launch_bounds__(256) void gemm_kernel(
    const float* __restrict__ m1, const float* __restrict__ m2,
    const float* __restrict__ wc,
    const float* __restrict__ Q, const float* __restrict__ D,
    float* __restrict__ out) {

    __shared__ __align__(16) char sA[BM * BK * 2];   // bf16, XOR-swizzled
    __shared__ __align__(16) char sB[BN * BK * 2];
    __shared__ float wcs[FEAT];

    const int tid = threadIdx.x;
    const int blk = blockIdx.x;
    const int b  = blk >> 8;                 // 256 tiles per batch (16x16)
    const int t  = blk & 255;
    const int tm = t >> 4, tn = t & 15;

    for (int i = tid; i < FEAT; i += 256) wcs[i] = wc[i];

    const float* Abase = m1 + ((size_t)b * S1 + (size_t)tm * BM) * FEAT;
    const float* Bbase = m2 + ((size_t)b * S2 + (size_t)tn * BN) * FEAT;

    const int lane = tid & 63;
    const int wave = tid >> 6;
    const int wm = wave >> 1, wn = wave & 1;  // 2x2 waves, each 64x64 out

    f32x4 acc[4][4];
#pragma unroll
    for (int m = 0; m < 4; ++m)
#pragma unroll
        for (int n = 0; n < 4; ++n) acc[m][n] = (f32x4)0.f;

    const int col4 = tid & 15;               // fixed float4-column per thread
    const int row0 = tid >> 4;               // rows row0 + 16*i

    __syncthreads();                          // wcs ready

    for (int ks = 0; ks < FEAT / BK; ++ks) {
        float4 wc4 = *(const float4*)&wcs[ks * BK + col4 * 4];
        const float4* Ak = (const float4*)(Abase + ks * BK);
        const float4* Bk = (const float4*)(Bbase + ks * BK);

        __syncthreads();                      // previous compute done
#pragma unroll
        for (int i = 0; i < 8; ++i) {
            int r = row0 + 16 * i;
            float4 a = Ak[(size_t)r * (FEAT / 4) + col4];
            us4 av = { f2bf(a.x * wc4.x), f2bf(a.y * wc4.y),
                       f2bf(a.z * wc4.z), f2bf(a.w * wc4.w) };
            int off = r * 128 + ((col4 * 8) ^ ((r & 7) << 4));
            *(us4*)(sA + off) = av;
        }
#pragma unroll
        for (int i = 0; i < 8; ++i) {
            int r = row0 + 16 * i;
            float4 v = Bk[(size_t)r * (FEAT / 4) + col4];
            us4 bv = { f2bf(v.x), f2bf(v.y), f2bf(v.z), f2bf(v.w) };
            int off = r * 128 + ((col4 * 8) ^ ((r & 7) << 4));
            *(us4*)(sB + off) = bv;
        }
        __syncthreads();                      // tiles ready

#pragma unroll
        for (int s = 0; s < 2; ++s) {         // two K=32 sub-steps
            bf16x8 af[4], bfr[4];
#pragma unroll
            for (int m = 0; m < 4; ++m) {
                int r = wm * 64 + m * 16 + (lane & 15);
                int coff = (s * 64 + (lane >> 4) * 16) ^ ((r & 7) << 4);
                af[m] = *(const bf16x8*)(sA + r * 128 + coff);
            }
#pragma unroll
            for (int n = 0; n < 4; ++n) {
                int r = wn * 64 + n * 16 + (lane & 15);
                int coff = (s * 64 + (lane >> 4) * 16) ^ ((r & 7) << 4);
                bfr[n] = *(const bf16x8*)(sB + r * 128 + coff);
            }
#pragma unroll
            for (int m = 0; m < 4; ++m)
#pragma unroll
                for (int n = 0; n < 4; ++n)
                    acc[m][n] = __builtin_amdgcn_mfma_f32_16x16x32_bf16(
                        af[m], bfr[n], acc[m][n], 0, 0, 0);
        }
    }

    // ---------------- epilogue: + Q[j] + D[k], store fp32 ----------------
    const float* Qb = Q + b * S1 + tm * BM;
    const float* Db = D + b * S2 + tn * BN;
    float dv[4];
#pragma unroll
    for (int n = 0; n < 4; ++n) dv[n] = Db[wn * 64 + n * 16 + (lane & 15)];

    const size_t outbase = ((size_t)b * S1 + (size_t)tm * BM) * S2 + (size_t)tn * BN;
#pragma unroll
    for (int m = 0; m < 4; ++m) {
#pragma unroll
        for (int i = 0; i < 4; ++i) {
            int rl = wm * 64 + m * 16 + (lane >> 4) * 4 + i;
            float qv = Qb[rl];
            float* orow = out + outbase + (size_t)rl * S2 + wn * 64;
#pragma unroll
            for (int n = 0; n < 4; ++n) {
                int cl = n * 16 + (lane & 15);
                orow[cl] = acc[m][n][i] + qv + dv[n];
            }
        }
    }
}

extern "C" void kernel_launch(void* const* d_in, const int* in_sizes, int n_in,
                              void* d_out, int out_size, void* d_ws, size_t ws_size,
                              hipStream_t stream) {
    const float* m1 = (const float*)d_in[0];
    const float* m2 = (const float*)d_in[1];
    const float* wq = (const float*)d_in[2];
    const float* wd = (const float*)d_in[3];
    const float* wc = (const float*)d_in[4];
    float* out = (float*)d_out;
    float* Q = (float*)d_ws;               // NB*S1 floats
    float* Dv = Q + NB * S1;               // NB*S2 floats (total 128 KB)

    qd_kernel<<<(2 * NB * S1) / 4, 256, 0, stream>>>(m1, m2, wq, wd, Q, Dv);
    gemm_kernel<<<NB * 256, 256, 0, stream>>>(m1, m2, wc, Q, Dv, out);
}

// Round 2
// 100.958 us; speedup vs baseline: 1.4022x; 1.4022x over previous
//
#include <hip/hip_runtime.h>
#include <hip/hip_bf16.h>

#define S1 2048
#define S2 2048
#define FEAT 768
#define NB 8
#define BM 128
#define BN 128
#define BK 64
#define KSTEPS (FEAT / BK)

typedef __attribute__((ext_vector_type(8))) short bf16x8;
typedef __attribute__((ext_vector_type(4))) float f32x4;
typedef __attribute__((ext_vector_type(4))) unsigned short us4;
typedef __attribute__((address_space(1))) const unsigned int gu32;
typedef __attribute__((address_space(3))) unsigned int lu32;

static __device__ __forceinline__ unsigned short f2bf(float x) {
    unsigned u = __builtin_bit_cast(unsigned, x);
    unsigned r = u + 0x7FFFu + ((u >> 16) & 1u);   // RNE
    return (unsigned short)(r >> 16);
}

// ---------------- prepass: A=bf16(m1*wc), B=bf16(m2), Q=m1@wq, D=m2@wd ----------------
__global__ __launch_bounds__(256) void conv_kernel(
    const float* __restrict__ m1, const float* __restrict__ m2,
    const float* __restrict__ wq, const float* __restrict__ wd,
    const float* __restrict__ wc,
    unsigned short* __restrict__ A, unsigned short* __restrict__ Bm,
    float* __restrict__ Q, float* __restrict__ D) {
    int wave = threadIdx.x >> 6;
    int lane = threadIdx.x & 63;
    int g = blockIdx.x * 4 + wave;               // 0 .. 2*NB*S1-1
    bool isA = (g < NB * S1);
    int row = isA ? g : g - NB * S1;
    const float* src = isA ? m1 : m2;
    const float* w   = isA ? wq : wd;
    unsigned short* dst = (isA ? A : Bm) + (size_t)row * FEAT;
    const float4* rp = (const float4*)(src + (size_t)row * FEAT);
    const float4* wp = (const float4*)w;
    const float4* cp = (const float4*)wc;
    float acc = 0.f;
#pragma unroll
    for (int i = 0; i < 3; ++i) {
        int idx = lane + 64 * i;
        float4 a = rp[idx];
        float4 b = wp[idx];
        acc += a.x * b.x + a.y * b.y + a.z * b.z + a.w * b.w;
        float4 c;
        if (isA) c = cp[idx]; else c = float4{1.f, 1.f, 1.f, 1.f};
        us4 v = { f2bf(a.x * c.x), f2bf(a.y * c.y),
                  f2bf(a.z * c.z), f2bf(a.w * c.w) };
        *(us4*)(dst + idx * 4) = v;
    }
#pragma unroll
    for (int s = 32; s; s >>= 1) acc += __shfl_xor(acc, s, 64);
    if (lane == 0) (isA ? Q : D)[row] = acc;
}

// ---------------- bf16 NT GEMM via global_load_lds, swizzled LDS ----------------
__global__ __launch_bounds__(256) void gemm_bf16_kernel(
    const unsigned short* __restrict__ A, const unsigned short* __restrict__ Bm,
    const float* __restrict__ Q, const float* __restrict__ D,
    float* __restrict__ out) {

    __shared__ __align__(16) char sA[BM * BK * 2];   // 16 KB, linear dest for gload_lds
    __shared__ __align__(16) char sB[BN * BK * 2];

    const int bid = blockIdx.x;
    // XCD-bijective swizzle (2048 % 8 == 0): XCD x owns batch x -> L2 locality
    const int swz = (bid & 7) * (NB * 256 / 8) + (bid >> 3);
    const int b  = swz >> 8;
    const int t  = swz & 255;
    const int tm = t >> 4, tn = t & 15;

    const int tid = threadIdx.x;
    const int lane = tid & 63;
    const int wave = tid >> 6;
    const int wm = wave >> 1, wn = wave & 1;     // 2x2 waves, 64x64 out each

    const char* Ab = (const char*)(A + ((size_t)b * S1 + (size_t)tm * BM) * FEAT);
    const char* Bb = (const char*)(Bm + ((size_t)b * S2 + (size_t)tn * BN) * FEAT);

    // staging: wave handles chunks {c*4+wave}, lane covers row chunk*8+(lane>>3),
    // source col pre-swizzled by the read-side involution cb ^= (r&7)<<4
    const int srow = lane >> 3;                          // r & 7
    const int scb  = 16 * ((lane & 7) ^ srow);           // inverse-swizzled col byte

    f32x4 acc[4][4];
#pragma unroll
    for (int m = 0; m < 4; ++m)
#pragma unroll
        for (int n = 0; n < 4; ++n) acc[m][n] = (f32x4)0.f;

    for (int ks = 0; ks < KSTEPS; ++ks) {
        __syncthreads();                                 // prev compute done
        const char* Aks = Ab + (size_t)ks * (BK * 2);
        const char* Bks = Bb + (size_t)ks * (BK * 2);
#pragma unroll
        for (int c = 0; c < 4; ++c) {
            int chunk = c * 4 + wave;
            int r = chunk * 8 + srow;
            __builtin_amdgcn_global_load_lds(
                (gu32*)(Aks + (size_t)r * (FEAT * 2) + scb),
                (lu32*)(sA + chunk * 1024), 16, 0, 0);
        }
#pragma unroll
        for (int c = 0; c < 4; ++c) {
            int chunk = c * 4 + wave;
            int r = chunk * 8 + srow;
            __builtin_amdgcn_global_load_lds(
                (gu32*)(Bks + (size_t)r * (FEAT * 2) + scb),
                (lu32*)(sB + chunk * 1024), 16, 0, 0);
        }
        __syncthreads();                                 // drains vmcnt, tiles ready

#pragma unroll
        for (int s = 0; s < 2; ++s) {                    // two K=32 sub-steps
            bf16x8 af[4], bfr[4];
#pragma unroll
            for (int m = 0; m < 4; ++m) {
                int r = wm * 64 + m * 16 + (lane & 15);
                int coff = (s * 64 + ((lane >> 4) * 16)) ^ ((r & 7) << 4);
                af[m] = *(const bf16x8*)(sA + r * 128 + coff);
            }
#pragma unroll
            for (int n = 0; n < 4; ++n) {
                int r = wn * 64 + n * 16 + (lane & 15);
                int coff = (s * 64 + ((lane >> 4) * 16)) ^ ((r & 7) << 4);
                bfr[n] = *(const bf16x8*)(sB + r * 128 + coff);
            }
#pragma unroll
            for (int m = 0; m < 4; ++m)
#pragma unroll
                for (int n = 0; n < 4; ++n)
                    acc[m][n] = __builtin_amdgcn_mfma_f32_16x16x32_bf16(
                        af[m], bfr[n], acc[m][n], 0, 0, 0);
        }
    }

    // ---------------- epilogue: + Q[j] + D[k], store fp32 ----------------
    const float* Qb = Q + b * S1 + tm * BM;
    const float* Db = D + b * S2 + tn * BN;
    float dv[4];
#pragma unroll
    for (int n = 0; n < 4; ++n) dv[n] = Db[wn * 64 + n * 16 + (lane & 15)];

    const size_t outbase = ((size_t)b * S1 + (size_t)tm * BM) * S2 + (size_t)tn * BN;
#pragma unroll
    for (int m = 0; m < 4; ++m) {
#pragma unroll
        for (int i = 0; i < 4; ++i) {
            int rl = wm * 64 + m * 16 + (lane >> 4) * 4 + i;
            float qv = Qb[rl];
            float* orow = out + outbase + (size_t)rl * S2 + wn * 64;
#pragma unroll
            for (int n = 0; n < 4; ++n) {
                int cl = n * 16 + (lane & 15);
                orow[cl] = acc[m][n][i] + qv + dv[n];
            }
        }
    }
}

// ================= fallback path (round-1, fp32 inputs) =================
__global__ __launch_bounds__(256) void qd_kernel(
    const float* __restrict__ m1, const float* __restrict__ m2,
    const float* __restrict__ wq, const float* __restrict__ wd,
    float* __restrict__ Q, float* __restrict__ D) {
    int wave = threadIdx.x >> 6;
    int lane = threadIdx.x & 63;
    int g = blockIdx.x * 4 + wave;
    const float* src; const float* w; float* dst; int row;
    if (g < NB * S1) { src = m1; w = wq; dst = Q; row = g; }
    else             { src = m2; w = wd; dst = D; row = g - NB * S1; }
    const float4* rp = (const float4*)(src + (size_t)row * FEAT);
    const float4* wp = (const float4*)w;
    float acc = 0.f;
#pragma unroll
    for (int i = 0; i < 3; ++i) {
        float4 a = rp[lane + 64 * i];
        float4 b = wp[lane + 64 * i];
        acc += a.x * b.x + a.y * b.y + a.z * b.z + a.w * b.w;
    }
#pragma unroll
    for (int s = 32; s; s >>= 1) acc += __shfl_xor(acc, s, 64);
    if (lane == 0) dst[row] = acc;
}

__global__ __launch_bounds__(256) void gemm_kernel(
    const float* __restrict__ m1, const float* __restrict__ m2,
    const float* __restrict__ wc,
    const float* __restrict__ Q, const float* __restrict__ D,
    float* __restrict__ out) {

    __shared__ __align__(16) char sA[BM * BK * 2];
    __shared__ __align__(16) char sB[BN * BK * 2];
    __shared__ float wcs[FEAT];

    const int tid = threadIdx.x;
    const int blk = blockIdx.x;
    const int b  = blk >> 8;
    const int t  = blk & 255;
    const int tm = t >> 4, tn = t & 15;

    for (int i = tid; i < FEAT; i += 256) wcs[i] = wc[i];

    const float* Abase = m1 + ((size_t)b * S1 + (size_t)tm * BM) * FEAT;
    const float* Bbase = m2 + ((size_t)b * S2 + (size_t)tn * BN) * FEAT;

    const int lane = tid & 63;
    const int wave = tid >> 6;
    const int wm = wave >> 1, wn = wave & 1;

    f32x4 acc[4][4];
#pragma unroll
    for (int m = 0; m < 4; ++m)
#pragma unroll
        for (int n = 0; n < 4; ++n) acc[m][n] = (f32x4)0.f;

    const int col4 = tid & 15;
    const int row0 = tid >> 4;

    __syncthreads();

    for (int ks = 0; ks < FEAT / BK; ++ks) {
        float4 wc4 = *(const float4*)&wcs[ks * BK + col4 * 4];
        const float4* Ak = (const float4*)(Abase + ks * BK);
        const float4* Bk = (const float4*)(Bbase + ks * BK);

        __syncthreads();
#pragma unroll
        for (int i = 0; i < 8; ++i) {
            int r = row0 + 16 * i;
            float4 a = Ak[(size_t)r * (FEAT / 4) + col4];
            us4 av = { f2bf(a.x * wc4.x), f2bf(a.y * wc4.y),
                       f2bf(a.z * wc4.z), f2bf(a.w * wc4.w) };
            int off = r * 128 + ((col4 * 8) ^ ((r & 7) << 4));
            *(us4*)(sA + off) = av;
        }
#pragma unroll
        for (int i = 0; i < 8; ++i) {
            int r = row0 + 16 * i;
            float4 v = Bk[(size_t)r * (FEAT / 4) + col4];
            us4 bv = { f2bf(v.x), f2bf(v.y), f2bf(v.z), f2bf(v.w) };
            int off = r * 128 + ((col4 * 8) ^ ((r & 7) << 4));
            *(us4*)(sB + off) = bv;
        }
        __syncthreads();

#pragma unroll
        for (int s = 0; s < 2; ++s) {
            bf16x8 af[4], bfr[4];
#pragma unroll
            for (int m = 0; m < 4; ++m) {
                int r = wm * 64 + m * 16 + (lane & 15);
                int coff = (s * 64 + (lane >> 4) * 16) ^ ((r & 7) << 4);
                af[m] = *(const bf16x8*)(sA + r * 128 + coff);
            }
#pragma unroll
            for (int n = 0; n < 4; ++n) {
                int r = wn * 64 + n * 16 + (lane & 15);
                int coff = (s * 64 + (lane >> 4) * 16) ^ ((r & 7) << 4);
                bfr[n] = *(const bf16x8*)(sB + r * 128 + coff);
            }
#pragma unroll
            for (int m = 0; m < 4; ++m)
#pragma unroll
                for (int n = 0; n < 4; ++n)
                    acc[m][n] = __builtin_amdgcn_mfma_f32_16x16x32_bf16(
                        af[m], bfr[n], acc[m][n], 0, 0, 0);
        }
    }

    const float* Qb = Q + b * S1 + tm * BM;
    const float* Db = D + b * S2 + tn * BN;
    float dv[4];
#pragma unroll
    for (int n = 0; n < 4; ++n) dv[n] = Db[wn * 64 + n * 16 + (lane & 15)];

    const size_t outbase = ((size_t)b * S1 + (size_t)tm * BM) * S2 + (size_t)tn * BN;
#pragma unroll
    for (int m = 0; m < 4; ++m) {
#pragma unroll
        for (int i = 0; i < 4; ++i) {
            int rl = wm * 64 + m * 16 + (lane >> 4) * 4 + i;
            float qv = Qb[rl];
            float* orow = out + outbase + (size_t)rl * S2 + wn * 64;
#pragma unroll
            for (int n = 0; n < 4; ++n) {
                int cl = n * 16 + (lane & 15);
                orow[cl] = acc[m][n][i] + qv + dv[n];
            }
        }
    }
}

extern "C" void kernel_launch(void* const* d_in, const int* in_sizes, int n_in,
                              void* d_out, int out_size, void* d_ws, size_t ws_size,
                              hipStream_t stream) {
    const float* m1 = (const float*)d_in[0];
    const float* m2 = (const float*)d_in[1];
    const float* wq = (const float*)d_in[2];
    const float* wd = (const float*)d_in[3];
    const float* wc = (const float*)d_in[4];
    float* out = (float*)d_out;

    const size_t elems = (size_t)NB * S1 * FEAT;
    const size_t need = 2 * elems * sizeof(unsigned short)
                      + (size_t)(NB * S1 + NB * S2) * sizeof(float);

    if (ws_size >= need) {
        unsigned short* Abuf = (unsigned short*)d_ws;
        unsigned short* Bbuf = Abuf + elems;
        float* Q  = (float*)(Bbuf + elems);
        float* Dv = Q + NB * S1;
        conv_kernel<<<(NB * S1 + NB * S2) / 4, 256, 0, stream>>>(
            m1, m2, wq, wd, wc, Abuf, Bbuf, Q, Dv);
        gemm_bf16_kernel<<<NB * 256, 256, 0, stream>>>(Abuf, Bbuf, Q, Dv, out);
    } else {
        float* Q  = (float*)d_ws;
        float* Dv = Q + NB * S1;
        qd_kernel<<<(2 * NB * S1) / 4, 256, 0, stream>>>(m1, m2, wq, wd, Q, Dv);
        gemm_kernel<<<NB * 256, 256, 0, stream>>>(m1, m2, wc, Q, Dv, out);
    }
}

// Round 3
// 95.296 us; speedup vs baseline: 1.4855x; 1.0594x over previous
//
#include <hip/hip_runtime.h>
#include <hip/hip_bf16.h>

#define S1 2048
#define S2 2048
#define FEAT 768
#define NB 8
#define BM 256
#define BN 256
#define BK 32
#define NKT (FEAT / BK)          // 24 K-tiles
#define KTILE_BYTES 32768        // A 16KB + B 16KB per K-tile
#define NBUF 4                   // 4-deep LDS pipeline, race-free

typedef __attribute__((ext_vector_type(8))) short bf16x8;
typedef __attribute__((ext_vector_type(4))) float f32x4;
typedef __attribute__((ext_vector_type(4))) unsigned short us4;
typedef __attribute__((address_space(1))) const unsigned int gu32;
typedef __attribute__((address_space(3))) unsigned int lu32;

static __device__ __forceinline__ unsigned short f2bf(float x) {
    unsigned u = __builtin_bit_cast(unsigned, x);
    unsigned r = u + 0x7FFFu + ((u >> 16) & 1u);   // RNE
    return (unsigned short)(r >> 16);
}

// ---------------- prepass: A=bf16(m1*wc), B=bf16(m2), Q=m1@wq, D=m2@wd ----------------
__global__ __launch_bounds__(256) void conv_kernel(
    const float* __restrict__ m1, const float* __restrict__ m2,
    const float* __restrict__ wq, const float* __restrict__ wd,
    const float* __restrict__ wc,
    unsigned short* __restrict__ A, unsigned short* __restrict__ Bm,
    float* __restrict__ Q, float* __restrict__ D) {
    int wave = threadIdx.x >> 6;
    int lane = threadIdx.x & 63;
    int g = blockIdx.x * 4 + wave;               // 0 .. 2*NB*S1-1
    bool isA = (g < NB * S1);
    int row = isA ? g : g - NB * S1;
    const float* src = isA ? m1 : m2;
    const float* w   = isA ? wq : wd;
    unsigned short* dst = (isA ? A : Bm) + (size_t)row * FEAT;
    const float4* rp = (const float4*)(src + (size_t)row * FEAT);
    const float4* wp = (const float4*)w;
    const float4* cp = (const float4*)wc;
    float acc = 0.f;
#pragma unroll
    for (int i = 0; i < 3; ++i) {
        int idx = lane + 64 * i;
        float4 a = rp[idx];
        float4 b = wp[idx];
        acc += a.x * b.x + a.y * b.y + a.z * b.z + a.w * b.w;
        float4 c;
        if (isA) c = cp[idx]; else c = float4{1.f, 1.f, 1.f, 1.f};
        us4 v = { f2bf(a.x * c.x), f2bf(a.y * c.y),
                  f2bf(a.z * c.z), f2bf(a.w * c.w) };
        *(us4*)(dst + idx * 4) = v;
    }
#pragma unroll
    for (int s = 32; s; s >>= 1) acc += __shfl_xor(acc, s, 64);
    if (lane == 0) (isA ? Q : D)[row] = acc;
}

// ---------------- 256x256 tile, BK=32, 4-buffer pipelined bf16 NT GEMM ----------------
// stage(kt): 4 global_load_lds per thread (A: 2 rounds of 128 rows, B: same).
// Each round: wave w covers rows 128r+16w..+15; lane covers (row srow, 16B col scol).
// LDS dest is linear (wave-uniform base + lane*16). Fragment reads are contiguous
// 1KB regions -> bank-conflict-free without swizzle.
#define STAGE(kt) do {                                                            \
    const int _buf = (kt) & (NBUF - 1);                                           \
    const char* _As = Ab + (kt) * (BK * 2);                                       \
    const char* _Bs = Bb + (kt) * (BK * 2);                                       \
    char* _lA = ldsb + _buf * KTILE_BYTES;                                        \
    char* _lB = _lA + 16384;                                                      \
    _Pragma("unroll")                                                             \
    for (int _r = 0; _r < 2; ++_r) {                                              \
        const int _rowb = _r * 128 + wave * 16;                                   \
        __builtin_amdgcn_global_load_lds(                                         \
            (gu32*)(_As + (size_t)(_rowb + srow) * (FEAT * 2) + scol),            \
            (lu32*)(_lA + _rowb * 64), 16, 0, 0);                                 \
        __builtin_amdgcn_global_load_lds(                                         \
            (gu32*)(_Bs + (size_t)(_rowb + srow) * (FEAT * 2) + scol),            \
            (lu32*)(_lB + _rowb * 64), 16, 0, 0);                                 \
    }                                                                             \
} while (0)

__global__ __launch_bounds__(512, 2) void gemm256_kernel(
    const unsigned short* __restrict__ A, const unsigned short* __restrict__ Bm,
    const float* __restrict__ Q, const float* __restrict__ D,
    float* __restrict__ out) {

    extern __shared__ __align__(16) char ldsb[];   // NBUF * 32 KB = 128 KB

    const int bid = blockIdx.x;                    // 512 blocks = 8 XCD * 64
    const int swz = (bid & 7) * 64 + (bid >> 3);   // bijective XCD swizzle
    const int b  = swz >> 6;                       // batch: one per XCD chunk
    const int t  = swz & 63;
    const int tm = t >> 3, tn = t & 7;

    const int tid  = threadIdx.x;
    const int lane = tid & 63;
    const int wave = tid >> 6;
    const int wm = wave >> 2, wn = wave & 3;       // 2x4 waves, 128x64 out each

    const char* Ab = (const char*)(A + ((size_t)b * S1 + (size_t)tm * BM) * FEAT);
    const char* Bb = (const char*)(Bm + ((size_t)b * S2 + (size_t)tn * BN) * FEAT);

    const int srow = lane >> 2;                    // staging row within 16-row chunk
    const int scol = (lane & 3) * 16;              // staging 16B col within 64B K-slice

    const int fr   = lane & 15;                    // fragment row
    const int fkg  = (lane >> 4) * 16;             // fragment K-group byte offset

    f32x4 acc[8][4];
#pragma unroll
    for (int m = 0; m < 8; ++m)
#pragma unroll
        for (int n = 0; n < 4; ++n) acc[m][n] = (f32x4)0.f;

    // prologue: fill pipeline with K-tiles 0 and 1
    STAGE(0);
    STAGE(1);
    asm volatile("s_waitcnt vmcnt(4)" ::: "memory");   // tile 0 landed (tile 1 in flight)
    __builtin_amdgcn_s_barrier();
    asm volatile("" ::: "memory");

#pragma unroll 4
    for (int kt = 0; kt < NKT; ++kt) {
        if (kt + 2 < NKT) STAGE(kt + 2);               // prefetch into buf (kt+2)&3

        const char* lA = ldsb + (kt & (NBUF - 1)) * KTILE_BYTES;
        const char* lB = lA + 16384;

        bf16x8 bfr[4], af[8];
#pragma unroll
        for (int n = 0; n < 4; ++n)
            bfr[n] = *(const bf16x8*)(lB + (wn * 64 + n * 16 + fr) * 64 + fkg);
#pragma unroll
        for (int m = 0; m < 8; ++m)
            af[m] = *(const bf16x8*)(lA + (wm * 128 + m * 16 + fr) * 64 + fkg);

        __builtin_amdgcn_s_setprio(1);
#pragma unroll
        for (int m = 0; m < 8; ++m)
#pragma unroll
            for (int n = 0; n < 4; ++n)
                acc[m][n] = __builtin_amdgcn_mfma_f32_16x16x32_bf16(
                    af[m], bfr[n], acc[m][n], 0, 0, 0);
        __builtin_amdgcn_s_setprio(0);

        if (kt + 1 < NKT) {
            // guarantee tile kt+1 fully landed; keep tile kt+2's 4 loads in flight
            if (kt + 2 < NKT) asm volatile("s_waitcnt vmcnt(4)" ::: "memory");
            else              asm volatile("s_waitcnt vmcnt(0)" ::: "memory");
            __builtin_amdgcn_s_barrier();
            asm volatile("" ::: "memory");
        }
    }

    // ---------------- epilogue: + Q[j] + D[k], store fp32 ----------------
    const float* Qb = Q + b * S1 + tm * BM;
    const float* Db = D + b * S2 + tn * BN;
    float dv[4];
#pragma unroll
    for (int n = 0; n < 4; ++n) dv[n] = Db[wn * 64 + n * 16 + fr];

    const size_t outbase = ((size_t)b * S1 + (size_t)tm * BM) * S2 + (size_t)tn * BN;
#pragma unroll
    for (int m = 0; m < 8; ++m) {
#pragma unroll
        for (int i = 0; i < 4; ++i) {
            int rl = wm * 128 + m * 16 + (lane >> 4) * 4 + i;
            float qv = Qb[rl];
            float* orow = out + outbase + (size_t)rl * S2 + wn * 64;
#pragma unroll
            for (int n = 0; n < 4; ++n)
                orow[n * 16 + fr] = acc[m][n][i] + qv + dv[n];
        }
    }
}

// ================= fallback path (round-1, fp32 inputs) =================
__global__ __launch_bounds__(256) void qd_kernel(
    const float* __restrict__ m1, const float* __restrict__ m2,
    const float* __restrict__ wq, const float* __restrict__ wd,
    float* __restrict__ Q, float* __restrict__ D) {
    int wave = threadIdx.x >> 6;
    int lane = threadIdx.x & 63;
    int g = blockIdx.x * 4 + wave;
    const float* src; const float* w; float* dst; int row;
    if (g < NB * S1) { src = m1; w = wq; dst = Q; row = g; }
    else             { src = m2; w = wd; dst = D; row = g - NB * S1; }
    const float4* rp = (const float4*)(src + (size_t)row * FEAT);
    const float4* wp = (const float4*)w;
    float acc = 0.f;
#pragma unroll
    for (int i = 0; i < 3; ++i) {
        float4 a = rp[lane + 64 * i];
        float4 b = wp[lane + 64 * i];
        acc += a.x * b.x + a.y * b.y + a.z * b.z + a.w * b.w;
    }
#pragma unroll
    for (int s = 32; s; s >>= 1) acc += __shfl_xor(acc, s, 64);
    if (lane == 0) dst[row] = acc;
}

__global__ __launch_bounds__(256) void gemm_kernel(
    const float* __restrict__ m1, const float* __restrict__ m2,
    const float* __restrict__ wc,
    const float* __restrict__ Q, const float* __restrict__ D,
    float* __restrict__ out) {

    __shared__ __align__(16) char sA[128 * 64 * 2];
    __shared__ __align__(16) char sB[128 * 64 * 2];
    __shared__ float wcs[FEAT];

    const int tid = threadIdx.x;
    const int blk = blockIdx.x;
    const int b  = blk >> 8;
    const int t  = blk & 255;
    const int tm = t >> 4, tn = t & 15;

    for (int i = tid; i < FEAT; i += 256) wcs[i] = wc[i];

    const float* Abase = m1 + ((size_t)b * S1 + (size_t)tm * 128) * FEAT;
    const float* Bbase = m2 + ((size_t)b * S2 + (size_t)tn * 128) * FEAT;

    const int lane = tid & 63;
    const int wave = tid >> 6;
    const int wm = wave >> 1, wn = wave & 1;

    f32x4 acc[4][4];
#pragma unroll
    for (int m = 0; m < 4; ++m)
#pragma unroll
        for (int n = 0; n < 4; ++n) acc[m][n] = (f32x4)0.f;

    const int col4 = tid & 15;
    const int row0 = tid >> 4;

    __syncthreads();

    for (int ks = 0; ks < FEAT / 64; ++ks) {
        float4 wc4 = *(const float4*)&wcs[ks * 64 + col4 * 4];
        const float4* Ak = (const float4*)(Abase + ks * 64);
        const float4* Bk = (const float4*)(Bbase + ks * 64);

        __syncthreads();
#pragma unroll
        for (int i = 0; i < 8; ++i) {
            int r = row0 + 16 * i;
            float4 a = Ak[(size_t)r * (FEAT / 4) + col4];
            us4 av = { f2bf(a.x * wc4.x), f2bf(a.y * wc4.y),
                       f2bf(a.z * wc4.z), f2bf(a.w * wc4.w) };
            int off = r * 128 + ((col4 * 8) ^ ((r & 7) << 4));
            *(us4*)(sA + off) = av;
        }
#pragma unroll
        for (int i = 0; i < 8; ++i) {
            int r = row0 + 16 * i;
            float4 v = Bk[(size_t)r * (FEAT / 4) + col4];
            us4 bv = { f2bf(v.x), f2bf(v.y), f2bf(v.z), f2bf(v.w) };
            int off = r * 128 + ((col4 * 8) ^ ((r & 7) << 4));
            *(us4*)(sB + off) = bv;
        }
        __syncthreads();

#pragma unroll
        for (int s = 0; s < 2; ++s) {
            bf16x8 af[4], bfr[4];
#pragma unroll
            for (int m = 0; m < 4; ++m) {
                int r = wm * 64 + m * 16 + (lane & 15);
                int coff = (s * 64 + (lane >> 4) * 16) ^ ((r & 7) << 4);
                af[m] = *(const bf16x8*)(sA + r * 128 + coff);
            }
#pragma unroll
            for (int n = 0; n < 4; ++n) {
                int r = wn * 64 + n * 16 + (lane & 15);
                int coff = (s * 64 + (lane >> 4) * 16) ^ ((r & 7) << 4);
                bfr[n] = *(const bf16x8*)(sB + r * 128 + coff);
            }
#pragma unroll
            for (int m = 0; m < 4; ++m)
#pragma unroll
                for (int n = 0; n < 4; ++n)
                    acc[m][n] = __builtin_amdgcn_mfma_f32_16x16x32_bf16(
                        af[m], bfr[n], acc[m][n], 0, 0, 0);
        }
    }

    const float* Qb = Q + b * S1 + tm * 128;
    const float* Db = D + b * S2 + tn * 128;
    float dv[4];
#pragma unroll
    for (int n = 0; n < 4; ++n) dv[n] = Db[wn * 64 + n * 16 + (lane & 15)];

    const size_t outbase = ((size_t)b * S1 + (size_t)tm * 128) * S2 + (size_t)tn * 128;
#pragma unroll
    for (int m = 0; m < 4; ++m) {
#pragma unroll
        for (int i = 0; i < 4; ++i) {
            int rl = wm * 64 + m * 16 + (lane >> 4) * 4 + i;
            float qv = Qb[rl];
            float* orow = out + outbase + (size_t)rl * S2 + wn * 64;
#pragma unroll
            for (int n = 0; n < 4; ++n) {
                int cl = n * 16 + (lane & 15);
                orow[cl] = acc[m][n][i] + qv + dv[n];
            }
        }
    }
}

extern "C" void kernel_launch(void* const* d_in, const int* in_sizes, int n_in,
                              void* d_out, int out_size, void* d_ws, size_t ws_size,
                              hipStream_t stream) {
    const float* m1 = (const float*)d_in[0];
    const float* m2 = (const float*)d_in[1];
    const float* wq = (const float*)d_in[2];
    const float* wd = (const float*)d_in[3];
    const float* wc = (const float*)d_in[4];
    float* out = (float*)d_out;

    const size_t elems = (size_t)NB * S1 * FEAT;
    const size_t need = 2 * elems * sizeof(unsigned short)
                      + (size_t)(NB * S1 + NB * S2) * sizeof(float);

    if (ws_size >= need) {
        unsigned short* Abuf = (unsigned short*)d_ws;
        unsigned short* Bbuf = Abuf + elems;
        float* Q  = (float*)(Bbuf + elems);
        float* Dv = Q + NB * S1;
        conv_kernel<<<(NB * S1 + NB * S2) / 4, 256, 0, stream>>>(
            m1, m2, wq, wd, wc, Abuf, Bbuf, Q, Dv);
        gemm256_kernel<<<NB * (S1 / BM) * (S2 / BN), 512, NBUF * KTILE_BYTES, stream>>>(
            Abuf, Bbuf, Q, Dv, out);
    } else {
        float* Q  = (float*)d_ws;
        float* Dv = Q + NB * S1;
        qd_kernel<<<(2 * NB * S1) / 4, 256, 0, stream>>>(m1, m2, wq, wd, Q, Dv);
        gemm_kernel<<<NB * 256, 256, 0, stream>>>(m1, m2, wc, Q, Dv, out);
    }
}

// Round 4
// 93.292 us; speedup vs baseline: 1.5174x; 1.0215x over previous
//
#include <hip/hip_runtime.h>
#include <hip/hip_bf16.h>

#define S1 2048
#define S2 2048
#define FEAT 768
#define NB 8
#define BM 256
#define BN 256
#define BK 32
#define NKT (FEAT / BK)          // 24 K-tiles
#define KTILE_BYTES 32768        // A 16KB + B 16KB per K-tile
#define NBUF 4                   // 4-deep LDS pipeline, race-free

typedef __attribute__((ext_vector_type(8))) short bf16x8;
typedef __attribute__((ext_vector_type(4))) float f32x4;
typedef __attribute__((ext_vector_type(4))) unsigned short us4;
typedef __attribute__((address_space(1))) const unsigned int gu32;
typedef __attribute__((address_space(3))) unsigned int lu32;

static __device__ __forceinline__ unsigned short f2bf(float x) {
    unsigned u = __builtin_bit_cast(unsigned, x);
    unsigned r = u + 0x7FFFu + ((u >> 16) & 1u);   // RNE
    return (unsigned short)(r >> 16);
}

// ---------------- prepass: A=bf16(m1*wc), B=bf16(m2), Q=m1@wq, D=m2@wd ----------------
__global__ __launch_bounds__(256) void conv_kernel(
    const float* __restrict__ m1, const float* __restrict__ m2,
    const float* __restrict__ wq, const float* __restrict__ wd,
    const float* __restrict__ wc,
    unsigned short* __restrict__ A, unsigned short* __restrict__ Bm,
    float* __restrict__ Q, float* __restrict__ D) {
    int wave = threadIdx.x >> 6;
    int lane = threadIdx.x & 63;
    int g = blockIdx.x * 4 + wave;               // 0 .. 2*NB*S1-1
    bool isA = (g < NB * S1);
    int row = isA ? g : g - NB * S1;
    const float* src = isA ? m1 : m2;
    const float* w   = isA ? wq : wd;
    unsigned short* dst = (isA ? A : Bm) + (size_t)row * FEAT;
    const float4* rp = (const float4*)(src + (size_t)row * FEAT);
    const float4* wp = (const float4*)w;
    const float4* cp = (const float4*)wc;
    float acc = 0.f;
#pragma unroll
    for (int i = 0; i < 3; ++i) {
        int idx = lane + 64 * i;
        float4 a = rp[idx];
        float4 b = wp[idx];
        acc += a.x * b.x + a.y * b.y + a.z * b.z + a.w * b.w;
        float4 c;
        if (isA) c = cp[idx]; else c = float4{1.f, 1.f, 1.f, 1.f};
        us4 v = { f2bf(a.x * c.x), f2bf(a.y * c.y),
                  f2bf(a.z * c.z), f2bf(a.w * c.w) };
        *(us4*)(dst + idx * 4) = v;
    }
#pragma unroll
    for (int s = 32; s; s >>= 1) acc += __shfl_xor(acc, s, 64);
    if (lane == 0) (isA ? Q : D)[row] = acc;
}

// ---------------- 256x256 tile, BK=32, 4-buffer pipelined bf16 NT GEMM ----------------
// LDS layout: row r (0..255) x 64B, 4 slots of 16B per row. Slot-XOR swizzle
// s' = s ^ ((r>>1)&3): applied on the global SOURCE col for global_load_lds
// (linear LDS dest, rule #21) and on the ds_read col. Read bank =
// (fr&1)*16 + s'*4, s' cycles all 4 slots across even rows -> 2-way = free.
#define STAGE(kt) do {                                                            \
    const int _buf = (kt) & (NBUF - 1);                                           \
    const char* _As = Ab + (kt) * (BK * 2);                                       \
    const char* _Bs = Bb + (kt) * (BK * 2);                                       \
    char* _lA = ldsb + _buf * KTILE_BYTES;                                        \
    char* _lB = _lA + 16384;                                                      \
    _Pragma("unroll")                                                             \
    for (int _r = 0; _r < 2; ++_r) {                                              \
        const int _rowb = _r * 128 + wave * 16;                                   \
        __builtin_amdgcn_global_load_lds(                                         \
            (gu32*)(_As + (size_t)(_rowb + srow) * (FEAT * 2) + scolsw),          \
            (lu32*)(_lA + _rowb * 64), 16, 0, 0);                                 \
        __builtin_amdgcn_global_load_lds(                                         \
            (gu32*)(_Bs + (size_t)(_rowb + srow) * (FEAT * 2) + scolsw),          \
            (lu32*)(_lB + _rowb * 64), 16, 0, 0);                                 \
    }                                                                             \
} while (0)

#define LOADFRAGS(set, ktidx) do {                                                \
    const char* _lA = ldsb + ((ktidx) & (NBUF - 1)) * KTILE_BYTES;                \
    const char* _lB = _lA + 16384;                                                \
    _Pragma("unroll")                                                             \
    for (int _n = 0; _n < 4; ++_n)                                                \
        bfx[set][_n] = *(const bf16x8*)(_lB + (wn * 64 + _n * 16 + fr) * 64 + fkb);\
    _Pragma("unroll")                                                             \
    for (int _m = 0; _m < 8; ++_m)                                                \
        afr[set][_m] = *(const bf16x8*)(_lA + (wm * 128 + _m * 16 + fr) * 64 + fkb);\
} while (0)

__global__ __launch_bounds__(512, 2) void gemm256_kernel(
    const unsigned short* __restrict__ A, const unsigned short* __restrict__ Bm,
    const float* __restrict__ Q, const float* __restrict__ D,
    float* __restrict__ out) {

    extern __shared__ __align__(16) char ldsb[];   // NBUF * 32 KB = 128 KB

    const int bid = blockIdx.x;                    // 512 blocks = 8 XCD * 64
    const int swz = (bid & 7) * 64 + (bid >> 3);   // bijective XCD swizzle
    const int b  = swz >> 6;                       // batch: one per XCD chunk
    const int t  = swz & 63;
    const int tm = t >> 3, tn = t & 7;

    const int tid  = threadIdx.x;
    const int lane = tid & 63;
    const int wave = tid >> 6;
    const int wm = wave >> 2, wn = wave & 3;       // 2x4 waves, 128x64 out each

    const char* Ab = (const char*)(A + ((size_t)b * S1 + (size_t)tm * BM) * FEAT);
    const char* Bb = (const char*)(Bm + ((size_t)b * S2 + (size_t)tn * BN) * FEAT);

    const int srow   = lane >> 2;                              // staging row in 16-row chunk
    const int scolsw = (((lane & 3) ^ ((lane >> 3) & 3)) * 16);// pre-swizzled source col

    const int fr  = lane & 15;                                 // fragment row
    const int fkb = (((lane >> 4) ^ ((lane >> 1) & 3)) * 16);  // swizzled frag col byte

    f32x4 acc[8][4];
#pragma unroll
    for (int m = 0; m < 8; ++m)
#pragma unroll
        for (int n = 0; n < 4; ++n) acc[m][n] = (f32x4)0.f;

    bf16x8 afr[2][8];
    bf16x8 bfx[2][4];

    // prologue: fill pipeline with K-tiles 0..2; guarantee tiles 0,1 landed
    STAGE(0);
    STAGE(1);
    STAGE(2);
    asm volatile("s_waitcnt vmcnt(4)" ::: "memory");
    __builtin_amdgcn_s_barrier();
    asm volatile("" ::: "memory");
    LOADFRAGS(0, 0);

#pragma unroll 2
    for (int kt = 0; kt < NKT; ++kt) {
        const int cur = kt & 1, nxt = cur ^ 1;
        if (kt + 3 < NKT) STAGE(kt + 3);           // write buf[(kt+3)&3] (= buf[(kt-1)&3], read 2 barriers ago)
        if (kt + 1 < NKT) LOADFRAGS(nxt, kt + 1);  // tile kt+1 landed per prev iter's vmcnt

        __builtin_amdgcn_s_setprio(1);
#pragma unroll
        for (int m = 0; m < 8; ++m)
#pragma unroll
            for (int n = 0; n < 4; ++n)
                acc[m][n] = __builtin_amdgcn_mfma_f32_16x16x32_bf16(
                    afr[cur][m], bfx[cur][n], acc[m][n], 0, 0, 0);
        __builtin_amdgcn_s_setprio(0);

        if (kt + 1 < NKT) {
            // ensure tile kt+2 landed for next iter's frag read; keep kt+3 in flight
            if (kt + 3 < NKT) asm volatile("s_waitcnt vmcnt(4)" ::: "memory");
            else              asm volatile("s_waitcnt vmcnt(0)" ::: "memory");
            __builtin_amdgcn_s_barrier();
            asm volatile("" ::: "memory");
        }
    }

    // ---------------- epilogue: + Q[j] + D[k], store fp32 ----------------
    const float* Qb = Q + b * S1 + tm * BM;
    const float* Db = D + b * S2 + tn * BN;
    float dv[4];
#pragma unroll
    for (int n = 0; n < 4; ++n) dv[n] = Db[wn * 64 + n * 16 + fr];

    const size_t outbase = ((size_t)b * S1 + (size_t)tm * BM) * S2 + (size_t)tn * BN;
#pragma unroll
    for (int m = 0; m < 8; ++m) {
#pragma unroll
        for (int i = 0; i < 4; ++i) {
            int rl = wm * 128 + m * 16 + (lane >> 4) * 4 + i;
            float qv = Qb[rl];
            float* orow = out + outbase + (size_t)rl * S2 + wn * 64;
#pragma unroll
            for (int n = 0; n < 4; ++n)
                orow[n * 16 + fr] = acc[m][n][i] + qv + dv[n];
        }
    }
}

// ================= fallback path (round-1, fp32 inputs) =================
__global__ __launch_bounds__(256) void qd_kernel(
    const float* __restrict__ m1, const float* __restrict__ m2,
    const float* __restrict__ wq, const float* __restrict__ wd,
    float* __restrict__ Q, float* __restrict__ D) {
    int wave = threadIdx.x >> 6;
    int lane = threadIdx.x & 63;
    int g = blockIdx.x * 4 + wave;
    const float* src; const float* w; float* dst; int row;
    if (g < NB * S1) { src = m1; w = wq; dst = Q; row = g; }
    else             { src = m2; w = wd; dst = D; row = g - NB * S1; }
    const float4* rp = (const float4*)(src + (size_t)row * FEAT);
    const float4* wp = (const float4*)w;
    float acc = 0.f;
#pragma unroll
    for (int i = 0; i < 3; ++i) {
        float4 a = rp[lane + 64 * i];
        float4 b = wp[lane + 64 * i];
        acc += a.x * b.x + a.y * b.y + a.z * b.z + a.w * b.w;
    }
#pragma unroll
    for (int s = 32; s; s >>= 1) acc += __shfl_xor(acc, s, 64);
    if (lane == 0) dst[row] = acc;
}

__global__ __launch_bounds__(256) void gemm_kernel(
    const float* __restrict__ m1, const float* __restrict__ m2,
    const float* __restrict__ wc,
    const float* __restrict__ Q, const float* __restrict__ D,
    float* __restrict__ out) {

    __shared__ __align__(16) char sA[128 * 64 * 2];
    __shared__ __align__(16) char sB[128 * 64 * 2];
    __shared__ float wcs[FEAT];

    const int tid = threadIdx.x;
    const int blk = blockIdx.x;
    const int b  = blk >> 8;
    const int t  = blk & 255;
    const int tm = t >> 4, tn = t & 15;

    for (int i = tid; i < FEAT; i += 256) wcs[i] = wc[i];

    const float* Abase = m1 + ((size_t)b * S1 + (size_t)tm * 128) * FEAT;
    const float* Bbase = m2 + ((size_t)b * S2 + (size_t)tn * 128) * FEAT;

    const int lane = tid & 63;
    const int wave = tid >> 6;
    const int wm = wave >> 1, wn = wave & 1;

    f32x4 acc[4][4];
#pragma unroll
    for (int m = 0; m < 4; ++m)
#pragma unroll
        for (int n = 0; n < 4; ++n) acc[m][n] = (f32x4)0.f;

    const int col4 = tid & 15;
    const int row0 = tid >> 4;

    __syncthreads();

    for (int ks = 0; ks < FEAT / 64; ++ks) {
        float4 wc4 = *(const float4*)&wcs[ks * 64 + col4 * 4];
        const float4* Ak = (const float4*)(Abase + ks * 64);
        const float4* Bk = (const float4*)(Bbase + ks * 64);

        __syncthreads();
#pragma unroll
        for (int i = 0; i < 8; ++i) {
            int r = row0 + 16 * i;
            float4 a = Ak[(size_t)r * (FEAT / 4) + col4];
            us4 av = { f2bf(a.x * wc4.x), f2bf(a.y * wc4.y),
                       f2bf(a.z * wc4.z), f2bf(a.w * wc4.w) };
            int off = r * 128 + ((col4 * 8) ^ ((r & 7) << 4));
            *(us4*)(sA + off) = av;
        }
#pragma unroll
        for (int i = 0; i < 8; ++i) {
            int r = row0 + 16 * i;
            float4 v = Bk[(size_t)r * (FEAT / 4) + col4];
            us4 bv = { f2bf(v.x), f2bf(v.y), f2bf(v.z), f2bf(v.w) };
            int off = r * 128 + ((col4 * 8) ^ ((r & 7) << 4));
            *(us4*)(sB + off) = bv;
        }
        __syncthreads();

#pragma unroll
        for (int s = 0; s < 2; ++s) {
            bf16x8 af[4], bfr[4];
#pragma unroll
            for (int m = 0; m < 4; ++m) {
                int r = wm * 64 + m * 16 + (lane & 15);
                int coff = (s * 64 + (lane >> 4) * 16) ^ ((r & 7) << 4);
                af[m] = *(const bf16x8*)(sA + r * 128 + coff);
            }
#pragma unroll
            for (int n = 0; n < 4; ++n) {
                int r = wn * 64 + n * 16 + (lane & 15);
                int coff = (s * 64 + (lane >> 4) * 16) ^ ((r & 7) << 4);
                bfr[n] = *(const bf16x8*)(sB + r * 128 + coff);
            }
#pragma unroll
            for (int m = 0; m < 4; ++m)
#pragma unroll
                for (int n = 0; n < 4; ++n)
                    acc[m][n] = __builtin_amdgcn_mfma_f32_16x16x32_bf16(
                        af[m], bfr[n], acc[m][n], 0, 0, 0);
        }
    }

    const float* Qb = Q + b * S1 + tm * 128;
    const float* Db = D + b * S2 + tn * 128;
    float dv[4];
#pragma unroll
    for (int n = 0; n < 4; ++n) dv[n] = Db[wn * 64 + n * 16 + (lane & 15)];

    const size_t outbase = ((size_t)b * S1 + (size_t)tm * 128) * S2 + (size_t)tn * 128;
#pragma unroll
    for (int m = 0; m < 4; ++m) {
#pragma unroll
        for (int i = 0; i < 4; ++i) {
            int rl = wm * 64 + m * 16 + (lane >> 4) * 4 + i;
            float qv = Qb[rl];
            float* orow = out + outbase + (size_t)rl * S2 + wn * 64;
#pragma unroll
            for (int n = 0; n < 4; ++n) {
                int cl = n * 16 + (lane & 15);
                orow[cl] = acc[m][n][i] + qv + dv[n];
            }
        }
    }
}

extern "C" void kernel_launch(void* const* d_in, const int* in_sizes, int n_in,
                              void* d_out, int out_size, void* d_ws, size_t ws_size,
                              hipStream_t stream) {
    const float* m1 = (const float*)d_in[0];
    const float* m2 = (const float*)d_in[1];
    const float* wq = (const float*)d_in[2];
    const float* wd = (const float*)d_in[3];
    const float* wc = (const float*)d_in[4];
    float* out = (float*)d_out;

    const size_t elems = (size_t)NB * S1 * FEAT;
    const size_t need = 2 * elems * sizeof(unsigned short)
                      + (size_t)(NB * S1 + NB * S2) * sizeof(float);

    if (ws_size >= need) {
        unsigned short* Abuf = (unsigned short*)d_ws;
        unsigned short* Bbuf = Abuf + elems;
        float* Q  = (float*)(Bbuf + elems);
        float* Dv = Q + NB * S1;
        conv_kernel<<<(NB * S1 + NB * S2) / 4, 256, 0, stream>>>(
            m1, m2, wq, wd, wc, Abuf, Bbuf, Q, Dv);
        gemm256_kernel<<<NB * (S1 / BM) * (S2 / BN), 512, NBUF * KTILE_BYTES, stream>>>(
            Abuf, Bbuf, Q, Dv, out);
    } else {
        float* Q  = (float*)d_ws;
        float* Dv = Q + NB * S1;
        qd_kernel<<<(2 * NB * S1) / 4, 256, 0, stream>>>(m1, m2, wq, wd, Q, Dv);
        gemm_kernel<<<NB * 256, 256, 0, stream>>>(m1, m2, wc, Q, Dv, out);
    }
}

// Round 5
// 93.270 us; speedup vs baseline: 1.5178x; 1.0002x over previous
//
#include <hip/hip_runtime.h>
#include <hip/hip_bf16.h>

#define S1 2048
#define S2 2048
#define FEAT 768
#define NB 8
#define BM 256
#define BN 256
#define BK 32
#define NKT (FEAT / BK)          // 24 K-tiles
#define KTILE_BYTES 32768        // A 16KB + B 16KB per K-tile
#define NBUF 4                   // 4-deep LDS pipeline, race-free

typedef __attribute__((ext_vector_type(8))) short bf16x8;
typedef __attribute__((ext_vector_type(4))) float f32x4;
typedef __attribute__((ext_vector_type(4))) unsigned short us4;
typedef __attribute__((address_space(1))) const unsigned int gu32;
typedef __attribute__((address_space(3))) unsigned int lu32;

static __device__ __forceinline__ unsigned short f2bf(float x) {
    unsigned u = __builtin_bit_cast(unsigned, x);
    unsigned r = u + 0x7FFFu + ((u >> 16) & 1u);   // RNE
    return (unsigned short)(r >> 16);
}

// ---------------- prepass: A=bf16(m1*wc), B=bf16(m2), Q=m1@wq, D=m2@wd ----------------
__global__ __launch_bounds__(256) void conv_kernel(
    const float* __restrict__ m1, const float* __restrict__ m2,
    const float* __restrict__ wq, const float* __restrict__ wd,
    const float* __restrict__ wc,
    unsigned short* __restrict__ A, unsigned short* __restrict__ Bm,
    float* __restrict__ Q, float* __restrict__ D) {
    int wave = threadIdx.x >> 6;
    int lane = threadIdx.x & 63;
    int g = blockIdx.x * 4 + wave;               // 0 .. 2*NB*S1-1
    bool isA = (g < NB * S1);
    int row = isA ? g : g - NB * S1;
    const float* src = isA ? m1 : m2;
    const float* w   = isA ? wq : wd;
    unsigned short* dst = (isA ? A : Bm) + (size_t)row * FEAT;
    const float4* rp = (const float4*)(src + (size_t)row * FEAT);
    const float4* wp = (const float4*)w;
    const float4* cp = (const float4*)wc;
    float acc = 0.f;
#pragma unroll
    for (int i = 0; i < 3; ++i) {
        int idx = lane + 64 * i;
        float4 a = rp[idx];
        float4 b = wp[idx];
        acc += a.x * b.x + a.y * b.y + a.z * b.z + a.w * b.w;
        float4 c;
        if (isA) c = cp[idx]; else c = float4{1.f, 1.f, 1.f, 1.f};
        us4 v = { f2bf(a.x * c.x), f2bf(a.y * c.y),
                  f2bf(a.z * c.z), f2bf(a.w * c.w) };
        *(us4*)(dst + idx * 4) = v;
    }
#pragma unroll
    for (int s = 32; s; s >>= 1) acc += __shfl_xor(acc, s, 64);
    if (lane == 0) (isA ? Q : D)[row] = acc;
}

// ---------------- 256x256 tile, BK=32, 4-buffer ring, 2-phase K-tile ----------------
// Slot-XOR swizzle s' = s ^ ((r>>1)&3): pre-swizzled on the global SOURCE col
// for global_load_lds (linear LDS dest, rule #21), same XOR on the ds_read col.
// Proven conflict-free in R4 (SQ_LDS_BANK_CONFLICT = 0).
#define STAGE_HALF(_src, _ldst) do {                                              \
    _Pragma("unroll")                                                             \
    for (int _r = 0; _r < 2; ++_r) {                                              \
        const int _rowb = _r * 128 + wave * 16;                                   \
        __builtin_amdgcn_global_load_lds(                                         \
            (gu32*)((_src) + (size_t)(_rowb + srow) * (FEAT * 2) + scolsw),       \
            (lu32*)((_ldst) + _rowb * 64), 16, 0, 0);                             \
    }                                                                             \
} while (0)

__global__ __launch_bounds__(512, 1) void gemm256_kernel(
    const unsigned short* __restrict__ A, const unsigned short* __restrict__ Bm,
    const float* __restrict__ Q, const float* __restrict__ D,
    float* __restrict__ out) {

    extern __shared__ __align__(16) char ldsb[];   // NBUF * 32 KB = 128 KB

    const int bid = blockIdx.x;                    // 512 blocks = 8 XCD * 64
    const int swz = (bid & 7) * 64 + (bid >> 3);   // bijective XCD swizzle
    const int b  = swz >> 6;                       // batch: one per XCD
    const int t  = swz & 63;
    const int tm = t >> 3, tn = t & 7;

    const int tid  = threadIdx.x;
    const int lane = tid & 63;
    const int wave = tid >> 6;
    const int wm = wave >> 2, wn = wave & 3;       // 2x4 waves, 128x64 out each

    const char* Ab = (const char*)(A + ((size_t)b * S1 + (size_t)tm * BM) * FEAT);
    const char* Bb = (const char*)(Bm + ((size_t)b * S2 + (size_t)tn * BN) * FEAT);

    const int srow   = lane >> 2;                              // staging row in 16-row chunk
    const int scolsw = (((lane & 3) ^ ((lane >> 3) & 3)) * 16);// pre-swizzled source col

    const int fr  = lane & 15;                                 // fragment row
    const int fkb = (((lane >> 4) ^ ((lane >> 1) & 3)) * 16);  // swizzled frag col byte

    f32x4 acc[8][4];
#pragma unroll
    for (int m = 0; m < 8; ++m)
#pragma unroll
        for (int n = 0; n < 4; ++n) acc[m][n] = (f32x4)0.f;

    bf16x8 afr[2][8];
    bf16x8 bfx[2][4];

    // prologue: stage K-tiles 0..2 (A,A,B,B order -> 4 vmem instr per tile)
#pragma unroll
    for (int pk = 0; pk < 3; ++pk) {
        char* lA = ldsb + pk * KTILE_BYTES;
        STAGE_HALF(Ab + pk * (BK * 2), lA);
        STAGE_HALF(Bb + pk * (BK * 2), lA + 16384);
    }
    asm volatile("s_waitcnt vmcnt(4)" ::: "memory");   // tiles 0,1 landed
    __builtin_amdgcn_s_barrier();
    asm volatile("" ::: "memory");
    {   // frags of K-tile 0 -> set 0
        const char* lA = ldsb;
        const char* lB = ldsb + 16384;
#pragma unroll
        for (int n = 0; n < 4; ++n)
            bfx[0][n] = *(const bf16x8*)(lB + (wn * 64 + n * 16 + fr) * 64 + fkb);
#pragma unroll
        for (int m = 0; m < 8; ++m)
            afr[0][m] = *(const bf16x8*)(lA + (wm * 128 + m * 16 + fr) * 64 + fkb);
    }

#pragma unroll 2
    for (int kt = 0; kt < NKT; ++kt) {
        const int cur = kt & 1, nxt = cur ^ 1;
        const int lk = kt + 3;                         // stage ring index
        const char* nA = ldsb + ((kt + 1) & 3) * KTILE_BYTES;  // frag src for kt+1
        const char* nB = nA + 16384;
        char* stA = ldsb + (lk & 3) * KTILE_BYTES;     // stage dst for kt+3

        // ---- phase 0: stage A-half, load B-frags + A-frags 0..1, 16 MFMA ----
        if (lk < NKT) STAGE_HALF(Ab + lk * (BK * 2), stA);
        if (kt + 1 < NKT) {
#pragma unroll
            for (int n = 0; n < 4; ++n)
                bfx[nxt][n] = *(const bf16x8*)(nB + (wn * 64 + n * 16 + fr) * 64 + fkb);
#pragma unroll
            for (int m = 0; m < 2; ++m)
                afr[nxt][m] = *(const bf16x8*)(nA + (wm * 128 + m * 16 + fr) * 64 + fkb);
        }
        __builtin_amdgcn_s_barrier();
        asm volatile("" ::: "memory");
        __builtin_amdgcn_s_setprio(1);
#pragma unroll
        for (int m = 0; m < 4; ++m)
#pragma unroll
            for (int n = 0; n < 4; ++n)
                acc[m][n] = __builtin_amdgcn_mfma_f32_16x16x32_bf16(
                    afr[cur][m], bfx[cur][n], acc[m][n], 0, 0, 0);
        __builtin_amdgcn_s_setprio(0);

        // ---- phase 1: stage B-half, load A-frags 2..7, 16 MFMA ----
        if (lk < NKT) STAGE_HALF(Bb + lk * (BK * 2), stA + 16384);
        if (kt + 1 < NKT) {
#pragma unroll
            for (int m = 2; m < 8; ++m)
                afr[nxt][m] = *(const bf16x8*)(nA + (wm * 128 + m * 16 + fr) * 64 + fkb);
        }
        __builtin_amdgcn_s_barrier();
        asm volatile("" ::: "memory");
        __builtin_amdgcn_s_setprio(1);
#pragma unroll
        for (int m = 4; m < 8; ++m)
#pragma unroll
            for (int n = 0; n < 4; ++n)
                acc[m][n] = __builtin_amdgcn_mfma_f32_16x16x32_bf16(
                    afr[cur][m], bfx[cur][n], acc[m][n], 0, 0, 0);
        __builtin_amdgcn_s_setprio(0);

        // ---- end of K-tile: counted vmcnt (never 0 until tail), publish ----
        if (kt + 1 < NKT) {
            if (lk < NKT) asm volatile("s_waitcnt vmcnt(4)" ::: "memory");
            else          asm volatile("s_waitcnt vmcnt(0)" ::: "memory");
            __builtin_amdgcn_s_barrier();
            asm volatile("" ::: "memory");
        }
    }

    // ---------------- epilogue: + Q[j] + D[k], store fp32 ----------------
    const float* Qb = Q + b * S1 + tm * BM;
    const float* Db = D + b * S2 + tn * BN;
    float dv[4];
#pragma unroll
    for (int n = 0; n < 4; ++n) dv[n] = Db[wn * 64 + n * 16 + fr];

    const size_t outbase = ((size_t)b * S1 + (size_t)tm * BM) * S2 + (size_t)tn * BN;
#pragma unroll
    for (int m = 0; m < 8; ++m) {
#pragma unroll
        for (int i = 0; i < 4; ++i) {
            int rl = wm * 128 + m * 16 + (lane >> 4) * 4 + i;
            float qv = Qb[rl];
            float* orow = out + outbase + (size_t)rl * S2 + wn * 64;
#pragma unroll
            for (int n = 0; n < 4; ++n)
                orow[n * 16 + fr] = acc[m][n][i] + qv + dv[n];
        }
    }
}

// ================= fallback path (round-1, fp32 inputs) =================
__global__ __launch_bounds__(256) void qd_kernel(
    const float* __restrict__ m1, const float* __restrict__ m2,
    const float* __restrict__ wq, const float* __restrict__ wd,
    float* __restrict__ Q, float* __restrict__ D) {
    int wave = threadIdx.x >> 6;
    int lane = threadIdx.x & 63;
    int g = blockIdx.x * 4 + wave;
    const float* src; const float* w; float* dst; int row;
    if (g < NB * S1) { src = m1; w = wq; dst = Q; row = g; }
    else             { src = m2; w = wd; dst = D; row = g - NB * S1; }
    const float4* rp = (const float4*)(src + (size_t)row * FEAT);
    const float4* wp = (const float4*)w;
    float acc = 0.f;
#pragma unroll
    for (int i = 0; i < 3; ++i) {
        float4 a = rp[lane + 64 * i];
        float4 b = wp[lane + 64 * i];
        acc += a.x * b.x + a.y * b.y + a.z * b.z + a.w * b.w;
    }
#pragma unroll
    for (int s = 32; s; s >>= 1) acc += __shfl_xor(acc, s, 64);
    if (lane == 0) dst[row] = acc;
}

__global__ __launch_bounds__(256) void gemm_kernel(
    const float* __restrict__ m1, const float* __restrict__ m2,
    const float* __restrict__ wc,
    const float* __restrict__ Q, const float* __restrict__ D,
    float* __restrict__ out) {

    __shared__ __align__(16) char sA[128 * 64 * 2];
    __shared__ __align__(16) char sB[128 * 64 * 2];
    __shared__ float wcs[FEAT];

    const int tid = threadIdx.x;
    const int blk = blockIdx.x;
    const int b  = blk >> 8;
    const int t  = blk & 255;
    const int tm = t >> 4, tn = t & 15;

    for (int i = tid; i < FEAT; i += 256) wcs[i] = wc[i];

    const float* Abase = m1 + ((size_t)b * S1 + (size_t)tm * 128) * FEAT;
    const float* Bbase = m2 + ((size_t)b * S2 + (size_t)tn * 128) * FEAT;

    const int lane = tid & 63;
    const int wave = tid >> 6;
    const int wm = wave >> 1, wn = wave & 1;

    f32x4 acc[4][4];
#pragma unroll
    for (int m = 0; m < 4; ++m)
#pragma unroll
        for (int n = 0; n < 4; ++n) acc[m][n] = (f32x4)0.f;

    const int col4 = tid & 15;
    const int row0 = tid >> 4;

    __syncthreads();

    for (int ks = 0; ks < FEAT / 64; ++ks) {
        float4 wc4 = *(const float4*)&wcs[ks * 64 + col4 * 4];
        const float4* Ak = (const float4*)(Abase + ks * 64);
        const float4* Bk = (const float4*)(Bbase + ks * 64);

        __syncthreads();
#pragma unroll
        for (int i = 0; i < 8; ++i) {
            int r = row0 + 16 * i;
            float4 a = Ak[(size_t)r * (FEAT / 4) + col4];
            us4 av = { f2bf(a.x * wc4.x), f2bf(a.y * wc4.y),
                       f2bf(a.z * wc4.z), f2bf(a.w * wc4.w) };
            int off = r * 128 + ((col4 * 8) ^ ((r & 7) << 4));
            *(us4*)(sA + off) = av;
        }
#pragma unroll
        for (int i = 0; i < 8; ++i) {
            int r = row0 + 16 * i;
            float4 v = Bk[(size_t)r * (FEAT / 4) + col4];
            us4 bv = { f2bf(v.x), f2bf(v.y), f2bf(v.z), f2bf(v.w) };
            int off = r * 128 + ((col4 * 8) ^ ((r & 7) << 4));
            *(us4*)(sB + off) = bv;
        }
        __syncthreads();

#pragma unroll
        for (int s = 0; s < 2; ++s) {
            bf16x8 af[4], bfr[4];
#pragma unroll
            for (int m = 0; m < 4; ++m) {
                int r = wm * 64 + m * 16 + (lane & 15);
                int coff = (s * 64 + (lane >> 4) * 16) ^ ((r & 7) << 4);
                af[m] = *(const bf16x8*)(sA + r * 128 + coff);
            }
#pragma unroll
            for (int n = 0; n < 4; ++n) {
                int r = wn * 64 + n * 16 + (lane & 15);
                int coff = (s * 64 + (lane >> 4) * 16) ^ ((r & 7) << 4);
                bfr[n] = *(const bf16x8*)(sB + r * 128 + coff);
            }
#pragma unroll
            for (int m = 0; m < 4; ++m)
#pragma unroll
                for (int n = 0; n < 4; ++n)
                    acc[m][n] = __builtin_amdgcn_mfma_f32_16x16x32_bf16(
                        af[m], bfr[n], acc[m][n], 0, 0, 0);
        }
    }

    const float* Qb = Q + b * S1 + tm * 128;
    const float* Db = D + b * S2 + tn * 128;
    float dv[4];
#pragma unroll
    for (int n = 0; n < 4; ++n) dv[n] = Db[wn * 64 + n * 16 + (lane & 15)];

    const size_t outbase = ((size_t)b * S1 + (size_t)tm * 128) * S2 + (size_t)tn * 128;
#pragma unroll
    for (int m = 0; m < 4; ++m) {
#pragma unroll
        for (int i = 0; i < 4; ++i) {
            int rl = wm * 64 + m * 16 + (lane >> 4) * 4 + i;
            float qv = Qb[rl];
            float* orow = out + outbase + (size_t)rl * S2 + wn * 64;
#pragma unroll
            for (int n = 0; n < 4; ++n) {
                int cl = n * 16 + (lane & 15);
                orow[cl] = acc[m][n][i] + qv + dv[n];
            }
        }
    }
}

extern "C" void kernel_launch(void* const* d_in, const int* in_sizes, int n_in,
                              void* d_out, int out_size, void* d_ws, size_t ws_size,
                              hipStream_t stream) {
    const float* m1 = (const float*)d_in[0];
    const float* m2 = (const float*)d_in[1];
    const float* wq = (const float*)d_in[2];
    const float* wd = (const float*)d_in[3];
    const float* wc = (const float*)d_in[4];
    float* out = (float*)d_out;

    const size_t elems = (size_t)NB * S1 * FEAT;
    const size_t need = 2 * elems * sizeof(unsigned short)
                      + (size_t)(NB * S1 + NB * S2) * sizeof(float);

    if (ws_size >= need) {
        unsigned short* Abuf = (unsigned short*)d_ws;
        unsigned short* Bbuf = Abuf + elems;
        float* Q  = (float*)(Bbuf + elems);
        float* Dv = Q + NB * S1;
        conv_kernel<<<(NB * S1 + NB * S2) / 4, 256, 0, stream>>>(
            m1, m2, wq, wd, wc, Abuf, Bbuf, Q, Dv);
        gemm256_kernel<<<NB * (S1 / BM) * (S2 / BN), 512, NBUF * KTILE_BYTES, stream>>>(
            Abuf, Bbuf, Q, Dv, out);
    } else {
        float* Q  = (float*)d_ws;
        float* Dv = Q + NB * S1;
        qd_kernel<<<(2 * NB * S1) / 4, 256, 0, stream>>>(m1, m2, wq, wd, Q, Dv);
        gemm_kernel<<<NB * 256, 256, 0, stream>>>(m1, m2, wc, Q, Dv, out);
    }
}